// Round 1
// baseline (433.044 us; speedup 1.0000x reference)
//
#include <hip/hip_runtime.h>

#define HD 128        // NUM_HEADS*OUT_DIM == IN_DIM
#define NHEADS 4
#define MBLK 128      // gemm rows per block
#define APITCH 136    // LDS pitch in ushorts

typedef __attribute__((ext_vector_type(8))) short bf16x8;
typedef __attribute__((ext_vector_type(4))) float f32x4;

__device__ __forceinline__ unsigned short f2bf(float x) {   // RNE
    union { float f; unsigned u; } a; a.f = x;
    unsigned r = a.u + 0x7fffu + ((a.u >> 16) & 1u);
    return (unsigned short)(r >> 16);
}

// ---------------- sort pipeline ----------------
__global__ void zero_counts(int* __restrict__ counts, int N) {
    int i = blockIdx.x * blockDim.x + threadIdx.x;
    if (i < N) counts[i] = 0;
}
__global__ void hist_dst(const int* __restrict__ dst, int* __restrict__ counts, int E) {
    int e0 = (blockIdx.x * blockDim.x + threadIdx.x) * 4;
    if (e0 + 3 < E) {
        int4 d4 = *(const int4*)&dst[e0];
        atomicAdd(&counts[d4.x], 1);
        atomicAdd(&counts[d4.y], 1);
        atomicAdd(&counts[d4.z], 1);
        atomicAdd(&counts[d4.w], 1);
    } else {
        for (int e = e0; e < E; e++) atomicAdd(&counts[dst[e]], 1);
    }
}
__global__ __launch_bounds__(256) void scan_pass1(const int* __restrict__ counts,
                                                  int* __restrict__ bsum, int N) {
    __shared__ int wsum[4];
    int tid = threadIdx.x;
    int i0 = blockIdx.x * 1024 + tid * 4;
    int s = 0;
#pragma unroll
    for (int j = 0; j < 4; j++) s += (i0 + j < N) ? counts[i0 + j] : 0;
#pragma unroll
    for (int off = 1; off < 64; off <<= 1) s += __shfl_xor(s, off);
    if ((tid & 63) == 0) wsum[tid >> 6] = s;
    __syncthreads();
    if (tid == 0) bsum[blockIdx.x] = wsum[0] + wsum[1] + wsum[2] + wsum[3];
}
__global__ __launch_bounds__(1024) void scan_pass2(int* __restrict__ bsum, int nb) {
    __shared__ int sm[1024];
    int tid = threadIdx.x;
    int orig = (tid < nb) ? bsum[tid] : 0;
    sm[tid] = orig;
    __syncthreads();
    for (int off = 1; off < 1024; off <<= 1) {
        int v = (tid >= off) ? sm[tid - off] : 0;
        __syncthreads();
        sm[tid] += v;
        __syncthreads();
    }
    if (tid < nb) bsum[tid] = sm[tid] - orig;   // exclusive
}
__global__ __launch_bounds__(256) void scan_pass3(const int* __restrict__ counts,
        const int* __restrict__ bsum, int* __restrict__ offsets, int* __restrict__ cursor,
        int N, int E) {
    __shared__ int wsum[4];
    int tid = threadIdx.x, lane = tid & 63, wid = tid >> 6;
    int i0 = blockIdx.x * 1024 + tid * 4;
    int v[4];
#pragma unroll
    for (int j = 0; j < 4; j++) v[j] = (i0 + j < N) ? counts[i0 + j] : 0;
    int local = v[0] + v[1] + v[2] + v[3];
    int incl = local;
#pragma unroll
    for (int off = 1; off < 64; off <<= 1) {
        int t = __shfl_up(incl, off);
        if (lane >= off) incl += t;
    }
    if (lane == 63) wsum[wid] = incl;
    __syncthreads();
    int base = bsum[blockIdx.x];
    for (int w = 0; w < wid; w++) base += wsum[w];
    int excl = base + incl - local;
#pragma unroll
    for (int j = 0; j < 4; j++) {
        if (i0 + j < N) { offsets[i0 + j] = excl; cursor[i0 + j] = excl; }
        excl += v[j];
    }
    if (blockIdx.x == 0 && tid == 0) offsets[N] = E;
}

// scatter: 4B record per edge = src index only. Logits are recomputed in node_agg
// from e_src/e_dst (L2-resident), so scatter does no gathers and writes 4B not 16B.
__global__ __launch_bounds__(256) void scatter_edges(
    const int* __restrict__ src, const int* __restrict__ dst,
    int* __restrict__ cursor, int* __restrict__ erec, int E)
{
    int e0 = (blockIdx.x * blockDim.x + threadIdx.x) * 4;
    if (e0 + 3 < E) {
        int4 s4 = *(const int4*)&src[e0];
        int4 d4 = *(const int4*)&dst[e0];
        int p0 = atomicAdd(&cursor[d4.x], 1);
        int p1 = atomicAdd(&cursor[d4.y], 1);
        int p2 = atomicAdd(&cursor[d4.z], 1);
        int p3 = atomicAdd(&cursor[d4.w], 1);
        erec[p0] = s4.x;
        erec[p1] = s4.y;
        erec[p2] = s4.z;
        erec[p3] = s4.w;
    } else {
        for (int e = e0; e < E; e++) {
            int pos = atomicAdd(&cursor[dst[e]], 1);
            erec[pos] = src[e];
        }
    }
}

// ---------------- logits from bf16 h (runs after gemm): 32 lanes/node ----------------
__global__ __launch_bounds__(256) void logits(
    const unsigned short* __restrict__ h,
    const float* __restrict__ attn_src, const float* __restrict__ attn_dst,
    float* __restrict__ e_src, float* __restrict__ e_dst, int N)
{
    int widx = (blockIdx.x * 256 + threadIdx.x) >> 6;
    int lane = threadIdx.x & 63;
    int sub = lane >> 5, sl = lane & 31;
    int n = widx * 2 + sub;
    if (n >= N) return;
    uint2 hv = ((const uint2*)h)[(size_t)n * 32 + sl];       // dims sl*4..sl*4+3
    float4 as = ((const float4*)attn_src)[sl];
    float4 ad = ((const float4*)attn_dst)[sl];
    float x0 = __uint_as_float(hv.x << 16);
    float x1 = __uint_as_float(hv.x & 0xffff0000u);
    float x2 = __uint_as_float(hv.y << 16);
    float x3 = __uint_as_float(hv.y & 0xffff0000u);
    float ps = x0 * as.x + x1 * as.y + x2 * as.z + x3 * as.w;
    float pd = x0 * ad.x + x1 * ad.y + x2 * ad.z + x3 * ad.w;
    // reduce over the 8 lanes of each head (sl = head*8 + j)
    ps += __shfl_xor(ps, 1); ps += __shfl_xor(ps, 2); ps += __shfl_xor(ps, 4);
    pd += __shfl_xor(pd, 1); pd += __shfl_xor(pd, 2); pd += __shfl_xor(pd, 4);
    if ((sl & 7) == 0) {
        int head = sl >> 3;
        e_src[n * 4 + head] = ps;
        e_dst[n * 4 + head] = pd;
    }
}

// ---------------- bf16 MFMA GEMM: h = feat @ fc_w.T (bf16 out) ----------------
__global__ __launch_bounds__(256, 2) void gemm_mfma(
    const float* __restrict__ feat, const float* __restrict__ fc_w,
    unsigned short* __restrict__ h, int N)
{
    __shared__ unsigned short As[MBLK * APITCH];
    __shared__ unsigned short Bs[HD * APITCH];
    const int tid = threadIdx.x;
    const int row0 = blockIdx.x * MBLK;

    for (int i = tid; i < 128 * 32; i += 256) {
        int o = i >> 5, j = i & 31;
        float4 v = ((const float4*)fc_w)[i];
        ushort4 u; u.x = f2bf(v.x); u.y = f2bf(v.y); u.z = f2bf(v.z); u.w = f2bf(v.w);
        *(ushort4*)&Bs[o * APITCH + j * 4] = u;
    }
    for (int i = tid; i < MBLK * 32; i += 256) {
        int r = i >> 5, j = i & 31;
        int rowg = row0 + r;
        float4 v = make_float4(0.f, 0.f, 0.f, 0.f);
        if (rowg < N) {
            v = ((const float4*)feat)[(size_t)rowg * 32 + j];
        }
        ushort4 u; u.x = f2bf(v.x); u.y = f2bf(v.y); u.z = f2bf(v.z); u.w = f2bf(v.w);
        *(ushort4*)&As[r * APITCH + j * 4] = u;
    }
    __syncthreads();

    const int w = tid >> 6, lane = tid & 63, quad = lane >> 4, lr = lane & 15;
    f32x4 acc[2][8];
#pragma unroll
    for (int rt = 0; rt < 2; rt++)
#pragma unroll
        for (int ct = 0; ct < 8; ct++) acc[rt][ct] = (f32x4){0.f, 0.f, 0.f, 0.f};

#pragma unroll
    for (int ks = 0; ks < 4; ks++) {
        const int k0 = ks * 32 + quad * 8;
        bf16x8 a0 = *(const bf16x8*)&As[(w * 32 + lr) * APITCH + k0];
        bf16x8 a1 = *(const bf16x8*)&As[(w * 32 + 16 + lr) * APITCH + k0];
        bf16x8 bf[8];
#pragma unroll
        for (int ct = 0; ct < 8; ct++)
            bf[ct] = *(const bf16x8*)&Bs[(ct * 16 + lr) * APITCH + k0];
#pragma unroll
        for (int ct = 0; ct < 8; ct++) {
            acc[0][ct] = __builtin_amdgcn_mfma_f32_16x16x32_bf16(a0, bf[ct], acc[0][ct], 0, 0, 0);
            acc[1][ct] = __builtin_amdgcn_mfma_f32_16x16x32_bf16(a1, bf[ct], acc[1][ct], 0, 0, 0);
        }
    }
#pragma unroll
    for (int rt = 0; rt < 2; rt++) {
#pragma unroll
        for (int ct = 0; ct < 8; ct++) {
            int col = ct * 16 + lr;
#pragma unroll
            for (int reg = 0; reg < 4; reg++) {
                int row = row0 + w * 32 + rt * 16 + quad * 4 + reg;
                if (row < N) h[(size_t)row * 128 + col] = f2bf(acc[rt][ct][reg]);
            }
        }
    }
}

// ---------------- per-node fused softmax + aggregation (4B records, recomputed logits) ----------------
__global__ __launch_bounds__(256) void node_agg(
    const int* __restrict__ erec, const int* __restrict__ offsets,
    const unsigned short* __restrict__ h,
    const float* __restrict__ e_src, const float* __restrict__ e_dst,
    const float* __restrict__ feat, float* __restrict__ out, int N)
{
    int n = (blockIdx.x * 256 + threadIdx.x) >> 6;
    int lane = threadIdx.x & 63;
    if (n >= N) return;
    int start = offsets[n], end = offsets[n + 1];
    const float* fptr = feat + (size_t)n * HD;
    if (start == end) {                           // residual only: out = feat
        if (lane < 32)
            ((float4*)(out + (size_t)n * HD))[lane] = ((const float4*)fptr)[lane];
        return;
    }

    const int hh = lane & 3;
    const int grp = lane >> 2;
    const float ed = e_dst[(size_t)n * 4 + hh];

    // phase 1: online softmax stats (lane = grp*4+hh), logits recomputed from e_src/e_dst
    float m_l = -3.0e38f, s_l = 0.f;
    for (int i = start + grp; i < end; i += 16) {
        int si = erec[i];
        float v = e_src[(size_t)si * 4 + hh] + ed;
        v = v > 0.f ? v : 0.2f * v;
        float mn = fmaxf(m_l, v);
        s_l = s_l * __expf(m_l - mn) + __expf(v - mn);
        m_l = mn;
    }
#pragma unroll
    for (int off = 4; off < 64; off <<= 1) {
        float mo = __shfl_xor(m_l, off), so = __shfl_xor(s_l, off);
        float mn = fmaxf(m_l, mo);
        s_l = s_l * __expf(m_l - mn) + so * __expf(mo - mn);
        m_l = mn;
    }
    const float inv_s = 1.0f / s_l;

    // phase 2: 4 edges in flight x 16 lanes x 16B h loads
    const int g = lane >> 4;
    const int q = lane & 15;
    const int head2 = q >> 2;
    float4 accA = make_float4(0.f, 0.f, 0.f, 0.f);
    float4 accB = make_float4(0.f, 0.f, 0.f, 0.f);
    for (int chunk = start; chunk < end; chunk += 16) {
        float wv = 0.f; int si_l = 0;
        if (chunk + grp < end) {
            si_l = erec[chunk + grp];
            float v = e_src[(size_t)si_l * 4 + hh] + ed;
            v = v > 0.f ? v : 0.2f * v;
            wv = __expf(v - m_l) * inv_s;
        }
#pragma unroll
        for (int t = 0; t < 4; t++) {
            int e_in = t * 4 + g;
            int si = __shfl(si_l, e_in * 4);
            float ww = __shfl(wv, e_in * 4 + head2);
            uint4 hv = *(const uint4*)&h[(size_t)si * 128 + q * 8];
            accA.x += ww * __uint_as_float(hv.x << 16);
            accA.y += ww * __uint_as_float(hv.x & 0xffff0000u);
            accA.z += ww * __uint_as_float(hv.y << 16);
            accA.w += ww * __uint_as_float(hv.y & 0xffff0000u);
            accB.x += ww * __uint_as_float(hv.z << 16);
            accB.y += ww * __uint_as_float(hv.z & 0xffff0000u);
            accB.z += ww * __uint_as_float(hv.w << 16);
            accB.w += ww * __uint_as_float(hv.w & 0xffff0000u);
        }
    }
#pragma unroll
    for (int off = 16; off < 64; off <<= 1) {
        accA.x += __shfl_xor(accA.x, off); accA.y += __shfl_xor(accA.y, off);
        accA.z += __shfl_xor(accA.z, off); accA.w += __shfl_xor(accA.w, off);
        accB.x += __shfl_xor(accB.x, off); accB.y += __shfl_xor(accB.y, off);
        accB.z += __shfl_xor(accB.z, off); accB.w += __shfl_xor(accB.w, off);
    }
    if (lane < 16) {
        const float4* f = (const float4*)fptr + lane * 2;
        float4 c0 = f[0], c1 = f[1];
        c0.x += accA.x; c0.y += accA.y; c0.z += accA.z; c0.w += accA.w;
        c1.x += accB.x; c1.y += accB.y; c1.z += accB.z; c1.w += accB.w;
        float4* o = (float4*)(out + (size_t)n * HD + lane * 8);
        o[0] = c0; o[1] = c1;
    }
}

extern "C" void kernel_launch(void* const* d_in, const int* in_sizes, int n_in,
                              void* d_out, int out_size, void* d_ws, size_t ws_size,
                              hipStream_t stream) {
    const float* feat     = (const float*)d_in[0];
    const float* fc_w     = (const float*)d_in[1];
    const float* attn_src = (const float*)d_in[2];
    const float* attn_dst = (const float*)d_in[3];
    const int*   src      = (const int*)d_in[4];
    const int*   dst      = (const int*)d_in[5];
    const int N = in_sizes[0] / HD;
    const int E = in_sizes[4];
    float* out = (float*)d_out;

    // ws: h_bf16[N*128] | e_src[N*4] | e_dst[N*4] | erec[E] int | counts[N] | offsets[N+1] | cursor[N] | bsum[1024]
    unsigned short* h = (unsigned short*)d_ws;
    float* e_src  = (float*)(h + (size_t)N * HD);
    float* e_dst  = e_src + (size_t)N * NHEADS;
    int* erec     = (int*)(e_dst + (size_t)N * NHEADS);
    int* counts   = erec + (size_t)E;
    int* offsets  = counts + N;
    int* cursor   = offsets + (N + 1);
    int* bsum     = cursor + N;

    const int nb = (N + 1023) / 1024;
    const int eq = (E + 3) / 4;

    zero_counts<<<(N + 255) / 256, 256, 0, stream>>>(counts, N);
    hist_dst<<<(eq + 255) / 256, 256, 0, stream>>>(dst, counts, E);
    scan_pass1<<<nb, 256, 0, stream>>>(counts, bsum, N);
    scan_pass2<<<1, 1024, 0, stream>>>(bsum, nb);
    scan_pass3<<<nb, 256, 0, stream>>>(counts, bsum, offsets, cursor, N, E);
    scatter_edges<<<(eq + 255) / 256, 256, 0, stream>>>(src, dst, cursor, erec, E);
    gemm_mfma<<<(N + MBLK - 1) / MBLK, 256, 0, stream>>>(feat, fc_w, h, N);
    logits<<<(N + 7) / 8, 256, 0, stream>>>(h, attn_src, attn_dst, e_src, e_dst, N);
    node_agg<<<(N + 3) / 4, 256, 0, stream>>>(erec, offsets, h, e_src, e_dst, feat, out, N);
}

// Round 2
// 340.210 us; speedup vs baseline: 1.2729x; 1.2729x over previous
//
#include <hip/hip_runtime.h>

#define HD 128        // NUM_HEADS*OUT_DIM == IN_DIM
#define NHEADS 4
#define MBLK 128      // gemm rows per block
#define APITCH 136    // LDS pitch in ushorts

typedef __attribute__((ext_vector_type(8))) short bf16x8;
typedef __attribute__((ext_vector_type(4))) float f32x4;

__device__ __forceinline__ unsigned short f2bf(float x) {   // RNE
    union { float f; unsigned u; } a; a.f = x;
    unsigned r = a.u + 0x7fffu + ((a.u >> 16) & 1u);
    return (unsigned short)(r >> 16);
}

// ---------------- sort pipeline ----------------
// hist + rank in ONE atomic pass: the histogram atomicAdd's return value IS the
// intra-bucket rank. 1 thread/edge for max memory-level parallelism.
__global__ void hist_rank(const int* __restrict__ dst, int* __restrict__ counts,
                          int* __restrict__ rank, int E) {
    int e = blockIdx.x * blockDim.x + threadIdx.x;
    if (e < E) rank[e] = atomicAdd(&counts[dst[e]], 1);
}
__global__ __launch_bounds__(256) void scan_pass1(const int* __restrict__ counts,
                                                  int* __restrict__ bsum, int N) {
    __shared__ int wsum[4];
    int tid = threadIdx.x;
    int i0 = blockIdx.x * 1024 + tid * 4;
    int s = 0;
#pragma unroll
    for (int j = 0; j < 4; j++) s += (i0 + j < N) ? counts[i0 + j] : 0;
#pragma unroll
    for (int off = 1; off < 64; off <<= 1) s += __shfl_xor(s, off);
    if ((tid & 63) == 0) wsum[tid >> 6] = s;
    __syncthreads();
    if (tid == 0) bsum[blockIdx.x] = wsum[0] + wsum[1] + wsum[2] + wsum[3];
}
__global__ __launch_bounds__(1024) void scan_pass2(int* __restrict__ bsum, int nb) {
    __shared__ int sm[1024];
    int tid = threadIdx.x;
    int orig = (tid < nb) ? bsum[tid] : 0;
    sm[tid] = orig;
    __syncthreads();
    for (int off = 1; off < 1024; off <<= 1) {
        int v = (tid >= off) ? sm[tid - off] : 0;
        __syncthreads();
        sm[tid] += v;
        __syncthreads();
    }
    if (tid < nb) bsum[tid] = sm[tid] - orig;   // exclusive
}
__global__ __launch_bounds__(256) void scan_pass3(const int* __restrict__ counts,
        const int* __restrict__ bsum, int* __restrict__ offsets, int N, int E) {
    __shared__ int wsum[4];
    int tid = threadIdx.x, lane = tid & 63, wid = tid >> 6;
    int i0 = blockIdx.x * 1024 + tid * 4;
    int v[4];
#pragma unroll
    for (int j = 0; j < 4; j++) v[j] = (i0 + j < N) ? counts[i0 + j] : 0;
    int local = v[0] + v[1] + v[2] + v[3];
    int incl = local;
#pragma unroll
    for (int off = 1; off < 64; off <<= 1) {
        int t = __shfl_up(incl, off);
        if (lane >= off) incl += t;
    }
    if (lane == 63) wsum[wid] = incl;
    __syncthreads();
    int base = bsum[blockIdx.x];
    for (int w = 0; w < wid; w++) base += wsum[w];
    int excl = base + incl - local;
#pragma unroll
    for (int j = 0; j < 4; j++) {
        if (i0 + j < N) offsets[i0 + j] = excl;
        excl += v[j];
    }
    if (blockIdx.x == 0 && tid == 0) offsets[N] = E;
}

// scatter: ATOMIC-FREE. pos = offsets[dst] + rank. 4B record = src index only.
// Pure loads + one fire-and-forget scattered 4B store per thread -> full MLP.
__global__ void scatter_edges(
    const int* __restrict__ src, const int* __restrict__ dst,
    const int* __restrict__ rank, const int* __restrict__ offsets,
    int* __restrict__ erec, int E)
{
    int e = blockIdx.x * blockDim.x + threadIdx.x;
    if (e >= E) return;
    erec[offsets[dst[e]] + rank[e]] = src[e];
}

// ---------------- logits from bf16 h (runs after gemm): 32 lanes/node ----------------
__global__ __launch_bounds__(256) void logits(
    const unsigned short* __restrict__ h,
    const float* __restrict__ attn_src, const float* __restrict__ attn_dst,
    float* __restrict__ e_src, float* __restrict__ e_dst, int N)
{
    int widx = (blockIdx.x * 256 + threadIdx.x) >> 6;
    int lane = threadIdx.x & 63;
    int sub = lane >> 5, sl = lane & 31;
    int n = widx * 2 + sub;
    if (n >= N) return;
    uint2 hv = ((const uint2*)h)[(size_t)n * 32 + sl];       // dims sl*4..sl*4+3
    float4 as = ((const float4*)attn_src)[sl];
    float4 ad = ((const float4*)attn_dst)[sl];
    float x0 = __uint_as_float(hv.x << 16);
    float x1 = __uint_as_float(hv.x & 0xffff0000u);
    float x2 = __uint_as_float(hv.y << 16);
    float x3 = __uint_as_float(hv.y & 0xffff0000u);
    float ps = x0 * as.x + x1 * as.y + x2 * as.z + x3 * as.w;
    float pd = x0 * ad.x + x1 * ad.y + x2 * ad.z + x3 * ad.w;
    // reduce over the 8 lanes of each head (sl = head*8 + j)
    ps += __shfl_xor(ps, 1); ps += __shfl_xor(ps, 2); ps += __shfl_xor(ps, 4);
    pd += __shfl_xor(pd, 1); pd += __shfl_xor(pd, 2); pd += __shfl_xor(pd, 4);
    if ((sl & 7) == 0) {
        int head = sl >> 3;
        e_src[n * 4 + head] = ps;
        e_dst[n * 4 + head] = pd;
    }
}

// ---------------- bf16 MFMA GEMM: h = feat @ fc_w.T (bf16 out) ----------------
__global__ __launch_bounds__(256, 2) void gemm_mfma(
    const float* __restrict__ feat, const float* __restrict__ fc_w,
    unsigned short* __restrict__ h, int N)
{
    __shared__ unsigned short As[MBLK * APITCH];
    __shared__ unsigned short Bs[HD * APITCH];
    const int tid = threadIdx.x;
    const int row0 = blockIdx.x * MBLK;

    for (int i = tid; i < 128 * 32; i += 256) {
        int o = i >> 5, j = i & 31;
        float4 v = ((const float4*)fc_w)[i];
        ushort4 u; u.x = f2bf(v.x); u.y = f2bf(v.y); u.z = f2bf(v.z); u.w = f2bf(v.w);
        *(ushort4*)&Bs[o * APITCH + j * 4] = u;
    }
    for (int i = tid; i < MBLK * 32; i += 256) {
        int r = i >> 5, j = i & 31;
        int rowg = row0 + r;
        float4 v = make_float4(0.f, 0.f, 0.f, 0.f);
        if (rowg < N) {
            v = ((const float4*)feat)[(size_t)rowg * 32 + j];
        }
        ushort4 u; u.x = f2bf(v.x); u.y = f2bf(v.y); u.z = f2bf(v.z); u.w = f2bf(v.w);
        *(ushort4*)&As[r * APITCH + j * 4] = u;
    }
    __syncthreads();

    const int w = tid >> 6, lane = tid & 63, quad = lane >> 4, lr = lane & 15;
    f32x4 acc[2][8];
#pragma unroll
    for (int rt = 0; rt < 2; rt++)
#pragma unroll
        for (int ct = 0; ct < 8; ct++) acc[rt][ct] = (f32x4){0.f, 0.f, 0.f, 0.f};

#pragma unroll
    for (int ks = 0; ks < 4; ks++) {
        const int k0 = ks * 32 + quad * 8;
        bf16x8 a0 = *(const bf16x8*)&As[(w * 32 + lr) * APITCH + k0];
        bf16x8 a1 = *(const bf16x8*)&As[(w * 32 + 16 + lr) * APITCH + k0];
        bf16x8 bf[8];
#pragma unroll
        for (int ct = 0; ct < 8; ct++)
            bf[ct] = *(const bf16x8*)&Bs[(ct * 16 + lr) * APITCH + k0];
#pragma unroll
        for (int ct = 0; ct < 8; ct++) {
            acc[0][ct] = __builtin_amdgcn_mfma_f32_16x16x32_bf16(a0, bf[ct], acc[0][ct], 0, 0, 0);
            acc[1][ct] = __builtin_amdgcn_mfma_f32_16x16x32_bf16(a1, bf[ct], acc[1][ct], 0, 0, 0);
        }
    }
#pragma unroll
    for (int rt = 0; rt < 2; rt++) {
#pragma unroll
        for (int ct = 0; ct < 8; ct++) {
            int col = ct * 16 + lr;
#pragma unroll
            for (int reg = 0; reg < 4; reg++) {
                int row = row0 + w * 32 + rt * 16 + quad * 4 + reg;
                if (row < N) h[(size_t)row * 128 + col] = f2bf(acc[rt][ct][reg]);
            }
        }
    }
}

// ---------------- per-node fused softmax + aggregation (4B records, recomputed logits) ----------------
__global__ __launch_bounds__(256) void node_agg(
    const int* __restrict__ erec, const int* __restrict__ offsets,
    const unsigned short* __restrict__ h,
    const float* __restrict__ e_src, const float* __restrict__ e_dst,
    const float* __restrict__ feat, float* __restrict__ out, int N)
{
    int n = (blockIdx.x * 256 + threadIdx.x) >> 6;
    int lane = threadIdx.x & 63;
    if (n >= N) return;
    int start = offsets[n], end = offsets[n + 1];
    const float* fptr = feat + (size_t)n * HD;
    if (start == end) {                           // residual only: out = feat
        if (lane < 32)
            ((float4*)(out + (size_t)n * HD))[lane] = ((const float4*)fptr)[lane];
        return;
    }

    const int hh = lane & 3;
    const int grp = lane >> 2;
    const float ed = e_dst[(size_t)n * 4 + hh];

    // phase 1: online softmax stats (lane = grp*4+hh), logits recomputed from e_src/e_dst
    float m_l = -3.0e38f, s_l = 0.f;
    for (int i = start + grp; i < end; i += 16) {
        int si = erec[i];
        float v = e_src[(size_t)si * 4 + hh] + ed;
        v = v > 0.f ? v : 0.2f * v;
        float mn = fmaxf(m_l, v);
        s_l = s_l * __expf(m_l - mn) + __expf(v - mn);
        m_l = mn;
    }
#pragma unroll
    for (int off = 4; off < 64; off <<= 1) {
        float mo = __shfl_xor(m_l, off), so = __shfl_xor(s_l, off);
        float mn = fmaxf(m_l, mo);
        s_l = s_l * __expf(m_l - mn) + so * __expf(mo - mn);
        m_l = mn;
    }
    const float inv_s = 1.0f / s_l;

    // phase 2: 4 edges in flight x 16 lanes x 16B h loads
    const int g = lane >> 4;
    const int q = lane & 15;
    const int head2 = q >> 2;
    float4 accA = make_float4(0.f, 0.f, 0.f, 0.f);
    float4 accB = make_float4(0.f, 0.f, 0.f, 0.f);
    for (int chunk = start; chunk < end; chunk += 16) {
        float wv = 0.f; int si_l = 0;
        if (chunk + grp < end) {
            si_l = erec[chunk + grp];
            float v = e_src[(size_t)si_l * 4 + hh] + ed;
            v = v > 0.f ? v : 0.2f * v;
            wv = __expf(v - m_l) * inv_s;
        }
#pragma unroll
        for (int t = 0; t < 4; t++) {
            int e_in = t * 4 + g;
            int si = __shfl(si_l, e_in * 4);
            float ww = __shfl(wv, e_in * 4 + head2);
            uint4 hv = *(const uint4*)&h[(size_t)si * 128 + q * 8];
            accA.x += ww * __uint_as_float(hv.x << 16);
            accA.y += ww * __uint_as_float(hv.x & 0xffff0000u);
            accA.z += ww * __uint_as_float(hv.y << 16);
            accA.w += ww * __uint_as_float(hv.y & 0xffff0000u);
            accB.x += ww * __uint_as_float(hv.z << 16);
            accB.y += ww * __uint_as_float(hv.z & 0xffff0000u);
            accB.z += ww * __uint_as_float(hv.w << 16);
            accB.w += ww * __uint_as_float(hv.w & 0xffff0000u);
        }
    }
#pragma unroll
    for (int off = 16; off < 64; off <<= 1) {
        accA.x += __shfl_xor(accA.x, off); accA.y += __shfl_xor(accA.y, off);
        accA.z += __shfl_xor(accA.z, off); accA.w += __shfl_xor(accA.w, off);
        accB.x += __shfl_xor(accB.x, off); accB.y += __shfl_xor(accB.y, off);
        accB.z += __shfl_xor(accB.z, off); accB.w += __shfl_xor(accB.w, off);
    }
    if (lane < 16) {
        const float4* f = (const float4*)fptr + lane * 2;
        float4 c0 = f[0], c1 = f[1];
        c0.x += accA.x; c0.y += accA.y; c0.z += accA.z; c0.w += accA.w;
        c1.x += accB.x; c1.y += accB.y; c1.z += accB.z; c1.w += accB.w;
        float4* o = (float4*)(out + (size_t)n * HD + lane * 8);
        o[0] = c0; o[1] = c1;
    }
}

extern "C" void kernel_launch(void* const* d_in, const int* in_sizes, int n_in,
                              void* d_out, int out_size, void* d_ws, size_t ws_size,
                              hipStream_t stream) {
    const float* feat     = (const float*)d_in[0];
    const float* fc_w     = (const float*)d_in[1];
    const float* attn_src = (const float*)d_in[2];
    const float* attn_dst = (const float*)d_in[3];
    const int*   src      = (const int*)d_in[4];
    const int*   dst      = (const int*)d_in[5];
    const int N = in_sizes[0] / HD;
    const int E = in_sizes[4];
    float* out = (float*)d_out;

    // ws: h_bf16[N*128] | e_src[N*4] | e_dst[N*4] | erec[E] int | counts[N] | offsets[N+1] | rank[E] | bsum[1024]
    unsigned short* h = (unsigned short*)d_ws;
    float* e_src  = (float*)(h + (size_t)N * HD);
    float* e_dst  = e_src + (size_t)N * NHEADS;
    int* erec     = (int*)(e_dst + (size_t)N * NHEADS);
    int* counts   = erec + (size_t)E;
    int* offsets  = counts + N;
    int* rank     = offsets + (N + 1);
    int* bsum     = rank + E;

    const int nb = (N + 1023) / 1024;

    hipMemsetAsync(counts, 0, (size_t)N * sizeof(int), stream);
    hist_rank<<<(E + 255) / 256, 256, 0, stream>>>(dst, counts, rank, E);
    scan_pass1<<<nb, 256, 0, stream>>>(counts, bsum, N);
    scan_pass2<<<1, 1024, 0, stream>>>(bsum, nb);
    scan_pass3<<<nb, 256, 0, stream>>>(counts, bsum, offsets, N, E);
    scatter_edges<<<(E + 255) / 256, 256, 0, stream>>>(src, dst, rank, offsets, erec, E);
    gemm_mfma<<<(N + MBLK - 1) / MBLK, 256, 0, stream>>>(feat, fc_w, h, N);
    logits<<<(N + 7) / 8, 256, 0, stream>>>(h, attn_src, attn_dst, e_src, e_dst, N);
    node_agg<<<(N + 3) / 4, 256, 0, stream>>>(erec, offsets, h, e_src, e_dst, feat, out, N);
}